// Round 7
// baseline (315.290 us; speedup 1.0000x reference)
//
#include <hip/hip_runtime.h>
#include <hip/hip_bf16.h>
#include <stdint.h>

#define IN_F 1024
#define OUT_F 1024
#define NG 8
#define KSPLINE 8192            // IN_F * NG
#define KDIM 9216               // KSPLINE + IN_F
#define KHALF 4608              // split-K half (72 tiles of 64)
#define M_ROWS 8192
#define LOG2E 1.4426950408889634f
// KC = 1.75 * sqrt(log2(e)) : basis = exp(-((xn-c)*1.75)^2) = 2^(-(xn*KC - c*KC)^2)
#define KC 2.1019642153762872f

#define A_BLOCKS (M_ROWS / 4)           // 2048 (4 rows per block, wave-per-row)
#define W_BLOCKS ((OUT_F * 2304) / 256) // 9216
#define RB (KDIM * 2)                   // W row bytes (18432)
#define GBOFF 131072                    // LDS offset of gamma/beta*KC table (8KB)

using half4v = __attribute__((ext_vector_type(4))) _Float16;
using half8  = __attribute__((ext_vector_type(8))) _Float16;
using f32x4  = __attribute__((ext_vector_type(4))) float;
using f32x2  = __attribute__((ext_vector_type(2))) float;

#define AS1 __attribute__((address_space(1)))
#define AS3 __attribute__((address_space(3)))

// ---- prep: blocks [0, A_BLOCKS): LN stats (mu,rstd) + silu table S;
//            blocks [A_BLOCKS, +W_BLOCKS): W f32->f16 convert.
// Spline basis is NOT materialized anymore — computed inside the GEMM.
// x / S / W / musig deliberately stay cached (gemm re-reads them from L2/L3).
__global__ __launch_bounds__(256) void prep_kernel(
        const float* __restrict__ x, const float* __restrict__ sw,
        const float* __restrict__ bw, _Float16* __restrict__ S,
        float* __restrict__ musig, _Float16* __restrict__ W) {
    if (blockIdx.x >= A_BLOCKS) {
        int idx = (blockIdx.x - A_BLOCKS) * 256 + threadIdx.x;  // one float4 each
        int o   = idx / 2304;
        int k4  = idx - o * 2304;
        f32x4 v;
        if (k4 < 2048) v = __builtin_nontemporal_load(&((const f32x4*)sw)[(size_t)o * 2048 + k4]);
        else           v = __builtin_nontemporal_load(&((const f32x4*)bw)[(size_t)o * 256 + (k4 - 2048)]);
        half4v h = { (_Float16)v.x, (_Float16)v.y, (_Float16)v.z, (_Float16)v.w };
        *(half4v*)(W + (size_t)idx * 4) = h;
        return;
    }
    const int wave = threadIdx.x >> 6, lane = threadIdx.x & 63;
    const int row = blockIdx.x * 4 + wave;
    const float* xr = x + (size_t)row * IN_F;

    float xv[16];
    float s = 0.0f, s2 = 0.0f;
#pragma unroll
    for (int j = 0; j < 16; ++j) {
        float v = xr[j * 64 + lane];
        xv[j] = v;
        s += v;
        s2 += v * v;
    }
#pragma unroll
    for (int off = 32; off > 0; off >>= 1) {
        s  += __shfl_xor(s, off);
        s2 += __shfl_xor(s2, off);
    }
    float mu   = s * (1.0f / IN_F);
    float var  = s2 * (1.0f / IN_F) - mu * mu;
    float rstd = rsqrtf(var + 1e-5f);
    if (lane == 0) {
        f32x2 ms; ms[0] = mu; ms[1] = rstd;
        ((f32x2*)musig)[row] = ms;
    }
    _Float16* Srow = S + (size_t)row * IN_F;
#pragma unroll
    for (int j = 0; j < 16; ++j) {
        float xs = xv[j];
        Srow[j * 64 + lane] = (_Float16)(xs / (1.0f + exp2f(-xs * LOG2E)));
    }
}

__device__ __forceinline__ half8 spline8(float xv, float mu, float rs, float gk, float bk) {
    const float cqg[8] = {
        -2.0000000f * KC, -1.4285715f * KC, -0.8571429f * KC, -0.2857143f * KC,
         0.2857143f * KC,  0.8571429f * KC,  1.4285715f * KC,  2.0000000f * KC };
    float xq = fmaf((xv - mu) * rs, gk, bk);
    half8 h;
#pragma unroll
    for (int g = 0; g < 8; ++g) {
        float d = xq - cqg[g];
        h[g] = (_Float16)__builtin_amdgcn_exp2f(-(d * d));
    }
    return h;
}

// ---------------- fused GEMM: C(8192x1024) = [basis(x)|silu(x)](8192x9216) * W^T
// 256x256 tile, 8 waves (2Mx4N, per-wave 128x64), BK=64, double-buffered 128KB
// LDS + 8KB gb-table, split-K=2. R3-verified 4-phase quadrant schedule, with
// the A-operand STAGING replaced per tile type:
//   spline tile (feature f per K-chunk): P0 loads 4 x-scalars (t+1);
//     P2 computes+ds_writes slots 0,1; P3 slots 2,3 (swizzled write, same
//     (row&7) XOR involution as the read side). vm count at P0 = 4.
//   silu tile: exact R3 gload path from compact S buffer. vm count = 2.
// B staging/waits unchanged: B0B1 at P1, B2B3 at P2, P3 proves B0B1(t+1) via
// vm(2); vmcnt never drains to 0 mid-loop. lgkmcnt(0) before P3's barrier
// publishes the ds_writes for t+1's readers.
__global__ __launch_bounds__(512, 2) void gemm_kernel(
        const _Float16* __restrict__ W, const _Float16* __restrict__ S,
        const float* __restrict__ x, const float* __restrict__ musig,
        const float* __restrict__ gamma, const float* __restrict__ beta,
        const float* __restrict__ bias, float* __restrict__ C,
        float* __restrict__ P, int ntiles, int gpz) {
    extern __shared__ __align__(16) char smem[];   // 2 x [A 32K | B 32K] + gb 8K
    const int tid  = threadIdx.x;
    const int wave = tid >> 6, lane = tid & 63;
    const int wm = wave >> 2, wn = wave & 3;       // 2M x 4N wave grid

    // bijective XCD swizzle (grid % 8 == 0): 4 bn-siblings per group
    const int lb = blockIdx.x;
    const int per_xcd = gridDim.x >> 5;
    const int xcd = lb & 7, sl = lb >> 3;
    const int g  = xcd * per_xcd + (sl >> 2);
    const int bn = sl & 3;
    const int bm = g / gpz;
    const int z  = g - bm * gpz;
    const int ksoff = z * KHALF;

    // ---- staging geometry (slot s covers 64 rows; rowbases A {0,128,64,192},
    // B {0,128,32,160}); lane chunk pre-swizzled for the gload paths.
    const int l8 = lane >> 3;
    const int chunkswz = ((lane & 7) ^ l8) << 4;
    const int gAr[4] = {0, 128, 64, 192};
    const int gB[4]  = {0, 128, 32, 160};
    const char* pB[4];
    const char* pS[4];
    const float* xp[4];
#pragma unroll
    for (int s = 0; s < 4; ++s) {
        pB[s] = (const char*)W + (size_t)(bn * 256 + gB[s] + (wave >> 2) * 64
                + (wave & 3) * 8 + l8) * RB + (size_t)ksoff * 2 + chunkswz;
        int arow = bm * 256 + gAr[s] + wave * 8 + l8;
        pS[s] = (const char*)S + (size_t)arow * (IN_F * 2) + chunkswz;
    }
    // compute-staging per-thread constants: row-in-slot r6, chunk c8
    const int r6 = tid >> 3;            // == wave*8 + l8
    const int c8 = tid & 7;
    const int wAbase = r6 * 128 + ((c8 ^ (r6 & 7)) << 4);
    float mu4[4], rs4[4];
#pragma unroll
    for (int s = 0; s < 4; ++s) {
        int arow = bm * 256 + gAr[s] + r6;
        xp[s] = x + (size_t)arow * IN_F;
        f32x2 ms = ((const f32x2*)musig)[arow];
        mu4[s] = ms[0]; rs4[s] = ms[1];
    }

#define STAGE_B(s, nb, colb) __builtin_amdgcn_global_load_lds( \
        (const AS1 void*)(pB[s] + (colb)), \
        (AS3 void*)(smem + (nb) + 32768 + (s) * 8192 + wave * 1024), 16, 0, 0)
#define STAGE_S(s, nb, colb) __builtin_amdgcn_global_load_lds( \
        (const AS1 void*)(pS[s] + (colb)), \
        (AS3 void*)(smem + (nb) + (s) * 8192 + wave * 1024), 16, 0, 0)

    // ---- ds_read offsets (swizzled) ----
    const int lm  = lane & 15;
    const int hi  = (lane >> 4) << 4;
    const int swz = (lm & 7) << 4;
    const int ck0 = (0  + hi) ^ swz;
    const int ck1 = (64 + hi) ^ swz;
    const int aB0 = (0 + wm) * 8192 + lm * 128;
    const int aB1 = (2 + wm) * 8192 + lm * 128;
    const int bB0 = 32768 + (0 + (wn >> 1)) * 8192 + ((wn & 1) * 32 + lm) * 128;
    const int bB1 = 32768 + (2 + (wn >> 1)) * 8192 + ((wn & 1) * 32 + lm) * 128;

    f32x4 acc[8][4] = {};

#define MFMA_QUAD(MB, NB2, Aa, Bb)                                              \
    __builtin_amdgcn_s_barrier();                                               \
    asm volatile("s_waitcnt lgkmcnt(0)" ::: "memory");                          \
    __builtin_amdgcn_sched_barrier(0);                                          \
    __builtin_amdgcn_s_setprio(1);                                              \
    _Pragma("unroll")                                                           \
    for (int n = 0; n < 2; ++n)                                                 \
        _Pragma("unroll")                                                       \
        for (int m = 0; m < 4; ++m)                                             \
            acc[(MB)+m][(NB2)+n] = __builtin_amdgcn_mfma_f32_16x16x32_f16(      \
                Aa[m][0], Bb[n][0], acc[(MB)+m][(NB2)+n], 0, 0, 0);             \
    _Pragma("unroll")                                                           \
    for (int n = 0; n < 2; ++n)                                                 \
        _Pragma("unroll")                                                       \
        for (int m = 0; m < 4; ++m)                                             \
            acc[(MB)+m][(NB2)+n] = __builtin_amdgcn_mfma_f32_16x16x32_f16(      \
                Aa[m][1], Bb[n][1], acc[(MB)+m][(NB2)+n], 0, 0, 0);             \
    __builtin_amdgcn_s_setprio(0);                                              \
    __builtin_amdgcn_s_barrier();

    // ---- prologue ----
    {   // gb table: {gamma*KC, beta*KC} for all 1024 features
        f32x2 t0; t0[0] = gamma[tid] * KC;       t0[1] = beta[tid] * KC;
        f32x2 t1; t1[0] = gamma[tid + 512] * KC; t1[1] = beta[tid + 512] * KC;
        *(f32x2*)(smem + GBOFF + tid * 8) = t0;
        *(f32x2*)(smem + GBOFF + (tid + 512) * 8) = t1;
    }
    const int f00 = z * 576 + c8;        // tile 0 is always spline
    float xf0[4];
#pragma unroll
    for (int s = 0; s < 4; ++s) xf0[s] = xp[s][f00];
    STAGE_B(0, 0, 0); STAGE_B(1, 0, 0); STAGE_B(2, 0, 0); STAGE_B(3, 0, 0);
    __syncthreads();                     // publish gb table (full drain, once)
    {
        f32x2 gb0 = *(const f32x2*)(smem + GBOFF + f00 * 8);
#pragma unroll
        for (int s = 0; s < 4; ++s) {
            half8 h = spline8(xf0[s], mu4[s], rs4[s], gb0[0], gb0[1]);
            *(half8*)(smem + s * 8192 + wAbase) = h;
        }
    }
    asm volatile("s_waitcnt lgkmcnt(0)" ::: "memory");
    __builtin_amdgcn_s_barrier();        // publish A(t0)

    for (int kt = 0; kt < ntiles; ++kt) {
        const int cb = (kt & 1) * 65536;
        const int nb = cb ^ 65536;
        const bool pref = (kt + 1 < ntiles);
        const int nk = ksoff + (kt + 1) * 64;
        const bool nsil = nk >= KSPLINE;              // type of tile t+1
        const size_t bcolb = (size_t)(kt + 1) * 128;
        const int fb = z * 576 + (kt + 1) * 8 + c8;   // spline feature (if !nsil)
        size_t scolb = 0;
        if (nsil) scolb = (size_t)(nk - KSPLINE) * 2;

        // ===== P0: issue t+1 A-staging inputs; frags A0A1+B0B1; MFMA(mf0-3,nf0-1)
        float xf[4];
        if (pref) {
            if (nsil) { STAGE_S(0, nb, scolb); STAGE_S(1, nb, scolb); }
            else {
#pragma unroll
                for (int s = 0; s < 4; ++s) xf[s] = xp[s][fb];
            }
        }
        half8 aF[4][2], bF[2][2];
#pragma unroll
        for (int m = 0; m < 4; ++m) {
            aF[m][0] = *(const half8*)(smem + cb + aB0 + m * 2048 + ck0);
            aF[m][1] = *(const half8*)(smem + cb + aB0 + m * 2048 + ck1);
        }
#pragma unroll
        for (int n = 0; n < 2; ++n) {
            bF[n][0] = *(const half8*)(smem + cb + bB0 + n * 2048 + ck0);
            bF[n][1] = *(const half8*)(smem + cb + bB0 + n * 2048 + ck1);
        }
        if (pref) {
            if (nsil) asm volatile("s_waitcnt vmcnt(2)" ::: "memory");  // B2B3(t)+A2A3(t) proven
            else      asm volatile("s_waitcnt vmcnt(4)" ::: "memory");  // ditto (4 xf newest)
        } else {
            asm volatile("s_waitcnt vmcnt(0)" ::: "memory");
        }
        asm volatile("s_waitcnt lgkmcnt(8)" ::: "memory");
        MFMA_QUAD(0, 0, aF, bF)

        // ===== P1: frags B2B3; stage B0B1(t+1); MFMA(mf0-3,nf2-3)
        half8 bG[2][2];
#pragma unroll
        for (int n = 0; n < 2; ++n) {
            bG[n][0] = *(const half8*)(smem + cb + bB1 + n * 2048 + ck0);
            bG[n][1] = *(const half8*)(smem + cb + bB1 + n * 2048 + ck1);
        }
        if (pref) { STAGE_B(0, nb, bcolb); STAGE_B(1, nb, bcolb); }
        MFMA_QUAD(0, 2, aF, bG)

        // ===== P2: frags A2A3; spline: compute+write slots 0,1; stage B2B3(t+1)
        half8 aG[4][2];
#pragma unroll
        for (int m = 0; m < 4; ++m) {
            aG[m][0] = *(const half8*)(smem + cb + aB1 + m * 2048 + ck0);
            aG[m][1] = *(const half8*)(smem + cb + aB1 + m * 2048 + ck1);
        }
        f32x2 gb;
        if (pref) {
            if (!nsil) {
                gb = *(const f32x2*)(smem + GBOFF + fb * 8);
                half8 h0 = spline8(xf[0], mu4[0], rs4[0], gb[0], gb[1]);
                half8 h1 = spline8(xf[1], mu4[1], rs4[1], gb[0], gb[1]);
                *(half8*)(smem + nb + 0 * 8192 + wAbase) = h0;
                *(half8*)(smem + nb + 1 * 8192 + wAbase) = h1;
            }
            STAGE_B(2, nb, bcolb); STAGE_B(3, nb, bcolb);
        }
        MFMA_QUAD(4, 0, aG, bF)

        // ===== P3: spline: compute+write slots 2,3; prove B0B1(t+1); silu:
        //          stage A2A3(t+1) from S. Publish ds_writes before barrier.
        if (pref) {
            if (!nsil) {
                half8 h2 = spline8(xf[2], mu4[2], rs4[2], gb[0], gb[1]);
                half8 h3 = spline8(xf[3], mu4[3], rs4[3], gb[0], gb[1]);
                *(half8*)(smem + nb + 2 * 8192 + wAbase) = h2;
                *(half8*)(smem + nb + 3 * 8192 + wAbase) = h3;
            }
            asm volatile("s_waitcnt vmcnt(2)" ::: "memory");   // B0B1(t+1) proven
            if (nsil) { STAGE_S(2, nb, scolb); STAGE_S(3, nb, scolb); }
        } else {
            asm volatile("s_waitcnt vmcnt(0)" ::: "memory");
        }
        asm volatile("s_waitcnt lgkmcnt(0)" ::: "memory");     // publish A writes
        MFMA_QUAD(4, 2, aG, bG)
    }

    // epilogue: C/D layout col = lane&15, row = (lane>>4)*4 + reg
    const int cn  = lane & 15;
    const int rm4 = (lane >> 4) * 4;
    float* dst = z ? P : C;
#pragma unroll
    for (int nf = 0; nf < 4; ++nf) {
        int col = bn * 256 + wn * 64 + nf * 16 + cn;
        float bv = z ? 0.0f : bias[col];
#pragma unroll
        for (int mf = 0; mf < 8; ++mf) {
            int row = bm * 256 + wm * 128 + mf * 16 + rm4;
            float* cp = dst + (size_t)row * OUT_F + col;
#pragma unroll
            for (int r = 0; r < 4; ++r)
                cp[(size_t)r * OUT_F] = acc[mf][nf][r] + bv;
        }
    }
}

// ---- split-K reduction: C += P (C already holds partial0 + bias) ----
__global__ __launch_bounds__(256) void reduce_kernel(float* __restrict__ C,
        const float* __restrict__ P) {
    const int n4 = M_ROWS * OUT_F / 4;
    float4* c4 = (float4*)C;
    const float4* p4 = (const float4*)P;
    for (int i = blockIdx.x * 256 + threadIdx.x; i < n4; i += 2048 * 256) {
        float4 a = c4[i];
        float4 b = p4[i];
        a.x += b.x; a.y += b.y; a.z += b.z; a.w += b.w;
        c4[i] = a;
    }
}

extern "C" void kernel_launch(void* const* d_in, const int* in_sizes, int n_in,
                              void* d_out, int out_size, void* d_ws, size_t ws_size,
                              hipStream_t stream) {
    const float* x     = (const float*)d_in[0];
    const float* gamma = (const float*)d_in[1];
    const float* beta  = (const float*)d_in[2];
    const float* sw    = (const float*)d_in[3];
    const float* bw    = (const float*)d_in[4];
    const float* bb    = (const float*)d_in[5];
    float* out = (float*)d_out;

    char* ws = (char*)d_ws;
    size_t offW = 0;
    size_t offS = (size_t)OUT_F * KDIM * 2;                       // 18.9 MB (W)
    size_t offM = offS + (size_t)M_ROWS * IN_F * 2;               // +16.8 MB (S)
    size_t offP = offM + (size_t)M_ROWS * 8;                      // +64 KB (musig)
    size_t need = offP + (size_t)M_ROWS * OUT_F * 4;              // +33.5 MB (P)
    _Float16* Wb = (_Float16*)(ws + offW);
    _Float16* Sb = (_Float16*)(ws + offS);
    float*    Mb = (float*)(ws + offM);
    float*    Pb = (float*)(ws + offP);
    const int split = (ws_size >= need);

    static int s_attr = 0;
    if (!s_attr) {
        (void)hipFuncSetAttribute(reinterpret_cast<const void*>(gemm_kernel),
                            hipFuncAttributeMaxDynamicSharedMemorySize, 139264);
        s_attr = 1;
    }

    prep_kernel<<<A_BLOCKS + W_BLOCKS, 256, 0, stream>>>(
        x, sw, bw, Sb, Mb, Wb);
    if (split) {
        gemm_kernel<<<256, 512, 139264, stream>>>(
            Wb, Sb, x, Mb, gamma, beta, bb, out, Pb, KHALF / 64, 2);
        reduce_kernel<<<2048, 256, 0, stream>>>(out, Pb);
    } else {
        gemm_kernel<<<128, 512, 139264, stream>>>(
            Wb, Sb, x, Mb, gamma, beta, bb, out, Pb, KDIM / 64, 1);
    }
}

// Round 8
// 304.185 us; speedup vs baseline: 1.0365x; 1.0365x over previous
//
#include <hip/hip_runtime.h>
#include <hip/hip_bf16.h>
#include <stdint.h>

#define IN_F 1024
#define OUT_F 1024
#define NG 8
#define KSPLINE 8192            // IN_F * NG
#define KDIM 9216               // KSPLINE + IN_F
#define KHALF 4608              // split-K half (72 tiles of 64)
#define M_ROWS 8192
#define LOG2E 1.4426950408889634f
// KC = 1.75 * sqrt(log2(e)) : basis = exp(-((xn-c)*1.75)^2) = 2^(-(xn*KC - c*KC)^2)
#define KC 2.1019642153762872f
#define CQ0 (-2.0f * KC)                 // scaled leftmost grid point
#define DQ  (0.5714285714285714f * KC)   // scaled grid spacing (1.2011224)
#define DQ2 1.4426950408889634f          // DQ*DQ == log2(e) exactly (1.75*4/7==1)
#define QCHAIN 0.1353352832366127f       // e^-2 == 2^(-2*DQ2)

#define A_BLOCKS (M_ROWS / 4)           // 2048 (4 rows per block, wave-per-row)
#define W_BLOCKS ((OUT_F * 2304) / 256) // 9216
#define RB (KDIM * 2)                   // W row bytes (18432)
#define GBOFF 131072                    // LDS offset of gamma/beta*KC table (8KB)

using half4v = __attribute__((ext_vector_type(4))) _Float16;
using half8  = __attribute__((ext_vector_type(8))) _Float16;
using f32x4  = __attribute__((ext_vector_type(4))) float;
using f32x2  = __attribute__((ext_vector_type(2))) float;

#define AS1 __attribute__((address_space(1)))
#define AS3 __attribute__((address_space(3)))

// ---- prep: blocks [0, A_BLOCKS): LN stats (mu,rstd) + silu table S;
//            blocks [A_BLOCKS, +W_BLOCKS): W f32->f16 convert.
__global__ __launch_bounds__(256) void prep_kernel(
        const float* __restrict__ x, const float* __restrict__ sw,
        const float* __restrict__ bw, _Float16* __restrict__ S,
        float* __restrict__ musig, _Float16* __restrict__ W) {
    if (blockIdx.x >= A_BLOCKS) {
        int idx = (blockIdx.x - A_BLOCKS) * 256 + threadIdx.x;  // one float4 each
        int o   = idx / 2304;
        int k4  = idx - o * 2304;
        f32x4 v;
        if (k4 < 2048) v = __builtin_nontemporal_load(&((const f32x4*)sw)[(size_t)o * 2048 + k4]);
        else           v = __builtin_nontemporal_load(&((const f32x4*)bw)[(size_t)o * 256 + (k4 - 2048)]);
        half4v h = { (_Float16)v.x, (_Float16)v.y, (_Float16)v.z, (_Float16)v.w };
        *(half4v*)(W + (size_t)idx * 4) = h;
        return;
    }
    const int wave = threadIdx.x >> 6, lane = threadIdx.x & 63;
    const int row = blockIdx.x * 4 + wave;
    const float* xr = x + (size_t)row * IN_F;

    float xv[16];
    float s = 0.0f, s2 = 0.0f;
#pragma unroll
    for (int j = 0; j < 16; ++j) {
        float v = xr[j * 64 + lane];
        xv[j] = v;
        s += v;
        s2 += v * v;
    }
#pragma unroll
    for (int off = 32; off > 0; off >>= 1) {
        s  += __shfl_xor(s, off);
        s2 += __shfl_xor(s2, off);
    }
    float mu   = s * (1.0f / IN_F);
    float var  = s2 * (1.0f / IN_F) - mu * mu;
    float rstd = rsqrtf(var + 1e-5f);
    if (lane == 0) {
        f32x2 ms; ms[0] = mu; ms[1] = rstd;
        ((f32x2*)musig)[row] = ms;
    }
    _Float16* Srow = S + (size_t)row * IN_F;
#pragma unroll
    for (int j = 0; j < 16; ++j) {
        float xs = xv[j];
        Srow[j * 64 + lane] = (_Float16)(xs / (1.0f + exp2f(-xs * LOG2E)));
    }
}

// geometric-chain RBF: b_g = 2^(-(xq - (CQ0 + g*DQ))^2) via
// b_{g+1} = b_g * r_g, r_{g+1} = r_g * e^-2 — 2 exp2 + 13 muls (vs 8 exp2).
// Chain underflow (xq>8) only where true basis < 5e-5 << tolerance.
__device__ __forceinline__ half8 spline8c(float xq) {
    float d0 = xq - CQ0;
    float b  = __builtin_amdgcn_exp2f(-(d0 * d0));
    float r  = __builtin_amdgcn_exp2f(fmaf(2.0f * DQ, d0, -DQ2));
    half8 h;
#pragma unroll
    for (int g = 0; g < 8; ++g) {
        h[g] = (_Float16)b;
        if (g < 7) { b = b * r; r = r * QCHAIN; }
    }
    return h;
}

// ---------------- fused GEMM: C(8192x1024) = [basis(x)|silu(x)](8192x9216)*W^T
// R7 structure, with spline compute MOVED INSIDE the P2/P3 MFMA quads
// (between k0/k1 MFMA halves) so the VALU hides under the matrix pipe, and
// the 8-exp2 basis replaced by the 2-exp2 geometric chain.
// Publish safety: each ds_write completes before the writer's next quad
// lgkmcnt(0) ("memory" asm fences compiler motion); slot0/1 readers are 1+
// barrier later (t+1 P0 after t P3-quad), slot2/3 readers 2+ barriers later.
__global__ __launch_bounds__(512, 2) void gemm_kernel(
        const _Float16* __restrict__ W, const _Float16* __restrict__ S,
        const float* __restrict__ x, const float* __restrict__ musig,
        const float* __restrict__ gamma, const float* __restrict__ beta,
        const float* __restrict__ bias, float* __restrict__ C,
        float* __restrict__ P, int ntiles, int gpz) {
    extern __shared__ __align__(16) char smem[];   // 2 x [A 32K | B 32K] + gb 8K
    const int tid  = threadIdx.x;
    const int wave = tid >> 6, lane = tid & 63;
    const int wm = wave >> 2, wn = wave & 3;       // 2M x 4N wave grid

    // bijective XCD swizzle (grid % 8 == 0): 4 bn-siblings per group
    const int lb = blockIdx.x;
    const int per_xcd = gridDim.x >> 5;
    const int xcd = lb & 7, sl = lb >> 3;
    const int g  = xcd * per_xcd + (sl >> 2);
    const int bn = sl & 3;
    const int bm = g / gpz;
    const int z  = g - bm * gpz;
    const int ksoff = z * KHALF;

    const int l8 = lane >> 3;
    const int chunkswz = ((lane & 7) ^ l8) << 4;
    const int gAr[4] = {0, 128, 64, 192};
    const int gB[4]  = {0, 128, 32, 160};
    const char* pB[4];
    const char* pS[4];
    const float* xp[4];
#pragma unroll
    for (int s = 0; s < 4; ++s) {
        pB[s] = (const char*)W + (size_t)(bn * 256 + gB[s] + (wave >> 2) * 64
                + (wave & 3) * 8 + l8) * RB + (size_t)ksoff * 2 + chunkswz;
        pS[s] = (const char*)S + (size_t)(bm * 256 + gAr[s] + wave * 8 + l8)
                * (IN_F * 2) + chunkswz;
    }
    // compute-staging per-thread constants: row-in-slot r6, chunk c8
    const int r6 = tid >> 3;            // == wave*8 + l8
    const int c8 = tid & 7;
    const int wAbase = r6 * 128 + ((c8 ^ (r6 & 7)) << 4);
    float mu4[4], rs4[4];
#pragma unroll
    for (int s = 0; s < 4; ++s) {
        int arow = bm * 256 + gAr[s] + r6;
        xp[s] = x + (size_t)arow * IN_F;
        f32x2 ms = ((const f32x2*)musig)[arow];
        mu4[s] = ms[0]; rs4[s] = ms[1];
    }

#define STAGE_B(s, nb, colb) __builtin_amdgcn_global_load_lds( \
        (const AS1 void*)(pB[s] + (colb)), \
        (AS3 void*)(smem + (nb) + 32768 + (s) * 8192 + wave * 1024), 16, 0, 0)
#define STAGE_S(s, nb, colb) __builtin_amdgcn_global_load_lds( \
        (const AS1 void*)(pS[s] + (colb)), \
        (AS3 void*)(smem + (nb) + (s) * 8192 + wave * 1024), 16, 0, 0)

    // ---- ds_read offsets (swizzled) ----
    const int lm  = lane & 15;
    const int hi  = (lane >> 4) << 4;
    const int swz = (lm & 7) << 4;
    const int ck0 = (0  + hi) ^ swz;
    const int ck1 = (64 + hi) ^ swz;
    const int aB0 = (0 + wm) * 8192 + lm * 128;
    const int aB1 = (2 + wm) * 8192 + lm * 128;
    const int bB0 = 32768 + (0 + (wn >> 1)) * 8192 + ((wn & 1) * 32 + lm) * 128;
    const int bB1 = 32768 + (2 + (wn >> 1)) * 8192 + ((wn & 1) * 32 + lm) * 128;

    f32x4 acc[8][4] = {};

#define MFMA_HALF(MB, NB2, Aa, Bb, KH)                                          \
    _Pragma("unroll")                                                           \
    for (int n = 0; n < 2; ++n)                                                 \
        _Pragma("unroll")                                                       \
        for (int m = 0; m < 4; ++m)                                             \
            acc[(MB)+m][(NB2)+n] = __builtin_amdgcn_mfma_f32_16x16x32_f16(      \
                Aa[m][KH], Bb[n][KH], acc[(MB)+m][(NB2)+n], 0, 0, 0);

#define QUAD_OPEN()                                                             \
    __builtin_amdgcn_s_barrier();                                               \
    asm volatile("s_waitcnt lgkmcnt(0)" ::: "memory");                          \
    __builtin_amdgcn_sched_barrier(0);                                          \
    __builtin_amdgcn_s_setprio(1);
#define QUAD_CLOSE()                                                            \
    __builtin_amdgcn_s_setprio(0);                                              \
    __builtin_amdgcn_s_barrier();

    // ---- prologue ----
    {   // gb table: {gamma*KC, beta*KC} for all 1024 features
        f32x2 t0; t0[0] = gamma[tid] * KC;       t0[1] = beta[tid] * KC;
        f32x2 t1; t1[0] = gamma[tid + 512] * KC; t1[1] = beta[tid + 512] * KC;
        *(f32x2*)(smem + GBOFF + tid * 8) = t0;
        *(f32x2*)(smem + GBOFF + (tid + 512) * 8) = t1;
    }
    const int f00 = z * 576 + c8;        // tile 0 is always spline
    float xf0[4];
#pragma unroll
    for (int s = 0; s < 4; ++s) xf0[s] = xp[s][f00];
    STAGE_B(0, 0, 0); STAGE_B(1, 0, 0); STAGE_B(2, 0, 0); STAGE_B(3, 0, 0);
    __syncthreads();                     // publish gb table (full drain, once)
    {
        f32x2 gb0 = *(const f32x2*)(smem + GBOFF + f00 * 8);
#pragma unroll
        for (int s = 0; s < 4; ++s) {
            half8 h = spline8c(fmaf((xf0[s] - mu4[s]) * rs4[s], gb0[0], gb0[1]));
            *(half8*)(smem + s * 8192 + wAbase) = h;
        }
    }
    asm volatile("s_waitcnt lgkmcnt(0)" ::: "memory");
    __builtin_amdgcn_s_barrier();        // publish A(t0)

    for (int kt = 0; kt < ntiles; ++kt) {
        const int cb = (kt & 1) * 65536;
        const int nb = cb ^ 65536;
        const bool pref = (kt + 1 < ntiles);
        const int nk = ksoff + (kt + 1) * 64;
        const bool nsil = nk >= KSPLINE;              // type of tile t+1
        const size_t bcolb = (size_t)(kt + 1) * 128;
        const int fb = z * 576 + (kt + 1) * 8 + c8;   // spline feature (if !nsil)
        size_t scolb = 0;
        if (nsil) scolb = (size_t)(nk - KSPLINE) * 2;

        // ===== P0 region: issue t+1 A-inputs; frags A0A1+B0B1 =====
        float xf[4];
        if (pref) {
            if (nsil) { STAGE_S(0, nb, scolb); STAGE_S(1, nb, scolb); }
            else {
#pragma unroll
                for (int s = 0; s < 4; ++s) xf[s] = xp[s][fb];
            }
        }
        half8 aF[4][2], bF[2][2];
#pragma unroll
        for (int m = 0; m < 4; ++m) {
            aF[m][0] = *(const half8*)(smem + cb + aB0 + m * 2048 + ck0);
            aF[m][1] = *(const half8*)(smem + cb + aB0 + m * 2048 + ck1);
        }
#pragma unroll
        for (int n = 0; n < 2; ++n) {
            bF[n][0] = *(const half8*)(smem + cb + bB0 + n * 2048 + ck0);
            bF[n][1] = *(const half8*)(smem + cb + bB0 + n * 2048 + ck1);
        }
        if (pref) {
            if (nsil) asm volatile("s_waitcnt vmcnt(2)" ::: "memory");  // proves B2B3(t)+S23(t)
            else      asm volatile("s_waitcnt vmcnt(4)" ::: "memory");  // proves B2B3(t) (4 xf newest)
        } else {
            asm volatile("s_waitcnt vmcnt(0)" ::: "memory");
        }
        asm volatile("s_waitcnt lgkmcnt(8)" ::: "memory");
        QUAD_OPEN();
        MFMA_HALF(0, 0, aF, bF, 0)
        MFMA_HALF(0, 0, aF, bF, 1)
        QUAD_CLOSE();

        // ===== P1 region: frags B2B3; gb-table read; stage B0B1(t+1) =====
        half8 bG[2][2];
#pragma unroll
        for (int n = 0; n < 2; ++n) {
            bG[n][0] = *(const half8*)(smem + cb + bB1 + n * 2048 + ck0);
            bG[n][1] = *(const half8*)(smem + cb + bB1 + n * 2048 + ck1);
        }
        f32x2 gb;
        if (pref && !nsil) gb = *(const f32x2*)(smem + GBOFF + fb * 8);
        if (pref) { STAGE_B(0, nb, bcolb); STAGE_B(1, nb, bcolb); }
        QUAD_OPEN();
        MFMA_HALF(0, 2, aF, bG, 0)
        MFMA_HALF(0, 2, aF, bG, 1)
        QUAD_CLOSE();

        // ===== P2 region: frags A2A3; stage B2B3(t+1) =====
        half8 aG[4][2];
#pragma unroll
        for (int m = 0; m < 4; ++m) {
            aG[m][0] = *(const half8*)(smem + cb + aB1 + m * 2048 + ck0);
            aG[m][1] = *(const half8*)(smem + cb + aB1 + m * 2048 + ck1);
        }
        if (pref) { STAGE_B(2, nb, bcolb); STAGE_B(3, nb, bcolb); }
        QUAD_OPEN();
        MFMA_HALF(4, 0, aG, bF, 0)
        if (pref && !nsil) {   // spline slots 0,1 — VALU hides under MFMA
            half8 h0 = spline8c(fmaf((xf[0] - mu4[0]) * rs4[0], gb[0], gb[1]));
            half8 h1 = spline8c(fmaf((xf[1] - mu4[1]) * rs4[1], gb[0], gb[1]));
            *(half8*)(smem + nb + 0 * 8192 + wAbase) = h0;
            *(half8*)(smem + nb + 1 * 8192 + wAbase) = h1;
        }
        MFMA_HALF(4, 0, aG, bF, 1)
        QUAD_CLOSE();

        // ===== P3 region: prove B0B1(t+1); silu: stage A2A3(t+1) =====
        if (pref) {
            asm volatile("s_waitcnt vmcnt(2)" ::: "memory");   // B0B1(t+1) proven
            if (nsil) { STAGE_S(2, nb, scolb); STAGE_S(3, nb, scolb); }
        } else {
            asm volatile("s_waitcnt vmcnt(0)" ::: "memory");
        }
        QUAD_OPEN();
        MFMA_HALF(4, 2, aG, bG, 0)
        if (pref && !nsil) {   // spline slots 2,3
            half8 h2 = spline8c(fmaf((xf[2] - mu4[2]) * rs4[2], gb[0], gb[1]));
            half8 h3 = spline8c(fmaf((xf[3] - mu4[3]) * rs4[3], gb[0], gb[1]));
            *(half8*)(smem + nb + 2 * 8192 + wAbase) = h2;
            *(half8*)(smem + nb + 3 * 8192 + wAbase) = h3;
        }
        MFMA_HALF(4, 2, aG, bG, 1)
        QUAD_CLOSE();
    }

    // epilogue: C/D layout col = lane&15, row = (lane>>4)*4 + reg
    const int cn  = lane & 15;
    const int rm4 = (lane >> 4) * 4;
    float* dst = z ? P : C;
#pragma unroll
    for (int nf = 0; nf < 4; ++nf) {
        int col = bn * 256 + wn * 64 + nf * 16 + cn;
        float bv = z ? 0.0f : bias[col];
#pragma unroll
        for (int mf = 0; mf < 8; ++mf) {
            int row = bm * 256 + wm * 128 + mf * 16 + rm4;
            float* cp = dst + (size_t)row * OUT_F + col;
#pragma unroll
            for (int r = 0; r < 4; ++r)
                cp[(size_t)r * OUT_F] = acc[mf][nf][r] + bv;
        }
    }
}

// ---- split-K reduction: C += P (C already holds partial0 + bias) ----
__global__ __launch_bounds__(256) void reduce_kernel(float* __restrict__ C,
        const float* __restrict__ P) {
    const int n4 = M_ROWS * OUT_F / 4;
    float4* c4 = (float4*)C;
    const float4* p4 = (const float4*)P;
    for (int i = blockIdx.x * 256 + threadIdx.x; i < n4; i += 2048 * 256) {
        float4 a = c4[i];
        float4 b = p4[i];
        a.x += b.x; a.y += b.y; a.z += b.z; a.w += b.w;
        c4[i] = a;
    }
}

extern "C" void kernel_launch(void* const* d_in, const int* in_sizes, int n_in,
                              void* d_out, int out_size, void* d_ws, size_t ws_size,
                              hipStream_t stream) {
    const float* x     = (const float*)d_in[0];
    const float* gamma = (const float*)d_in[1];
    const float* beta  = (const float*)d_in[2];
    const float* sw    = (const float*)d_in[3];
    const float* bw    = (const float*)d_in[4];
    const float* bb    = (const float*)d_in[5];
    float* out = (float*)d_out;

    char* ws = (char*)d_ws;
    size_t offW = 0;
    size_t offS = (size_t)OUT_F * KDIM * 2;                       // 18.9 MB (W)
    size_t offM = offS + (size_t)M_ROWS * IN_F * 2;               // +16.8 MB (S)
    size_t offP = offM + (size_t)M_ROWS * 8;                      // +64 KB (musig)
    size_t need = offP + (size_t)M_ROWS * OUT_F * 4;              // +33.5 MB (P)
    _Float16* Wb = (_Float16*)(ws + offW);
    _Float16* Sb = (_Float16*)(ws + offS);
    float*    Mb = (float*)(ws + offM);
    float*    Pb = (float*)(ws + offP);
    const int split = (ws_size >= need);

    static int s_attr = 0;
    if (!s_attr) {
        (void)hipFuncSetAttribute(reinterpret_cast<const void*>(gemm_kernel),
                            hipFuncAttributeMaxDynamicSharedMemorySize, 139264);
        s_attr = 1;
    }

    prep_kernel<<<A_BLOCKS + W_BLOCKS, 256, 0, stream>>>(
        x, sw, bw, Sb, Mb, Wb);
    if (split) {
        gemm_kernel<<<256, 512, 139264, stream>>>(
            Wb, Sb, x, Mb, gamma, beta, bb, out, Pb, KHALF / 64, 2);
        reduce_kernel<<<2048, 256, 0, stream>>>(out, Pb);
    } else {
        gemm_kernel<<<128, 512, 139264, stream>>>(
            Wb, Sb, x, Mb, gamma, beta, bb, out, Pb, KDIM / 64, 1);
    }
}

// Round 9
// 285.915 us; speedup vs baseline: 1.1027x; 1.0639x over previous
//
#include <hip/hip_runtime.h>
#include <hip/hip_bf16.h>
#include <stdint.h>

#define IN_F 1024
#define OUT_F 1024
#define NG 8
#define KSPLINE 8192            // IN_F * NG
#define KDIM 9216               // KSPLINE + IN_F
#define KHALF 4608              // split-K half (72 tiles of 64)
#define M_ROWS 8192
#define LOG2E 1.4426950408889634f
// KC = 1.75 * sqrt(log2(e)) : basis = exp(-((xn-c)*1.75)^2) = 2^(-(xn*KC - c*KC)^2)
#define KC 2.1019642153762872f
#define CQ0 (-2.0f * KC)                 // scaled leftmost grid point
#define DQ  (0.5714285714285714f * KC)   // scaled grid spacing
#define DQ2 1.4426950408889634f          // DQ*DQ == log2(e) exactly (1.75*4/7==1)
#define QCHAIN 0.1353352832366127f       // e^-2

// K-order permutation (basis region only; silu region identity). Applied
// IDENTICALLY to A columns and W columns -> invisible to the GEMM.
// p8(f) = (f>>8)*256 + (f&3)*64 + ((f>>2)&63)  [bijective per 256-block]

#define A_BLOCKS (M_ROWS / 4)           // 2048 (4 rows per block, wave-per-row)
#define WS_BLOCKS 4096                  // spline-W: 1M threads, 1 feature each
#define WSIL_BLOCKS 1024                // silu-W: 256K threads, 4 f32 each
#define RB (KDIM * 2)                   // A/W row bytes (18432)

using half4v = __attribute__((ext_vector_type(4))) _Float16;
using half8  = __attribute__((ext_vector_type(8))) _Float16;
using f32x4  = __attribute__((ext_vector_type(4))) float;

#define AS1 __attribute__((address_space(1)))
#define AS3 __attribute__((address_space(3)))

// geometric-chain RBF (validated R8, absmax 0.0625): 2 exp2 + 13 mul vs 8 exp2.
__device__ __forceinline__ half8 spline8c(float xq) {
    float d0 = xq - CQ0;
    float b  = __builtin_amdgcn_exp2f(-(d0 * d0));
    float r  = __builtin_amdgcn_exp2f(fmaf(2.0f * DQ, d0, -DQ2));
    half8 h;
#pragma unroll
    for (int g = 0; g < 8; ++g) {
        h[g] = (_Float16)b;
        if (g < 7) { b = b * r; r = r * QCHAIN; }
    }
    return h;
}

// ---- prep: [0,A_BLOCKS) build A rows (vectorized loads, permuted-coalesced
// stores); [A_BLOCKS,+WS) spline-W with permB; [.., +WSIL) silu-W identity.
__global__ __launch_bounds__(256) void prep_kernel(
        const float* __restrict__ x, const float* __restrict__ gamma,
        const float* __restrict__ beta, const float* __restrict__ sw,
        const float* __restrict__ bw, _Float16* __restrict__ A,
        _Float16* __restrict__ W) {
    const int b = blockIdx.x;
    if (b >= A_BLOCKS + WS_BLOCKS) {
        // silu-W: K pos 8192+d, identity order; float4 read, 8B write
        int t = (b - A_BLOCKS - WS_BLOCKS) * 256 + threadIdx.x;   // 0..256K
        int o = t >> 8, d4 = t & 255;
        f32x4 v = __builtin_nontemporal_load(&((const f32x4*)bw)[o * 256 + d4]);
        half4v h = { (_Float16)v.x, (_Float16)v.y, (_Float16)v.z, (_Float16)v.w };
        *(half4v*)(W + (size_t)o * KDIM + KSPLINE + d4 * 4) = h;
        return;
    }
    if (b >= A_BLOCKS) {
        // spline-W: one feature per thread; 32B coalesced read, 16B write
        // landing in 256B-contiguous runs under permB.
        int t = (b - A_BLOCKS) * 256 + threadIdx.x;               // 0..1M
        int o = t >> 10, f = t & 1023;
        const f32x4* src = &((const f32x4*)sw)[((size_t)o * 1024 + f) * 2];
        f32x4 v0 = __builtin_nontemporal_load(src);
        f32x4 v1 = __builtin_nontemporal_load(src + 1);
        half8 h = { (_Float16)v0.x, (_Float16)v0.y, (_Float16)v0.z, (_Float16)v0.w,
                    (_Float16)v1.x, (_Float16)v1.y, (_Float16)v1.z, (_Float16)v1.w };
        int p8 = (f >> 8) * 256 + (f & 3) * 64 + ((f >> 2) & 63);
        *(half8*)(W + (size_t)o * KDIM + p8 * 8) = h;
        return;
    }
    // ---- A path: wave per row; lane owns 4 consecutive features per j ----
    const int wave = threadIdx.x >> 6, lane = threadIdx.x & 63;
    const int row = b * 4 + wave;
    const f32x4* xr4 = (const f32x4*)(x + (size_t)row * IN_F);

    f32x4 xv[4];
    float s = 0.0f, s2 = 0.0f;
#pragma unroll
    for (int j = 0; j < 4; ++j) {
        f32x4 v = xr4[j * 64 + lane];
        xv[j] = v;
        s  += v.x + v.y + v.z + v.w;
        s2 += v.x * v.x + v.y * v.y + v.z * v.z + v.w * v.w;
    }
#pragma unroll
    for (int off = 32; off > 0; off >>= 1) {
        s  += __shfl_xor(s, off);
        s2 += __shfl_xor(s2, off);
    }
    float mu   = s * (1.0f / IN_F);
    float var  = s2 * (1.0f / IN_F) - mu * mu;
    float rstd = rsqrtf(var + 1e-5f);

    _Float16* Arow = A + (size_t)row * KDIM;
    _Float16* silu_out = Arow + KSPLINE;
#pragma unroll
    for (int j = 0; j < 4; ++j) {
        int idx = j * 64 + lane;
        f32x4 g  = ((const f32x4*)gamma)[idx];
        f32x4 bt = ((const f32x4*)beta)[idx];
        float xs4[4] = { xv[j].x, xv[j].y, xv[j].z, xv[j].w };
        float gg[4]  = { g.x, g.y, g.z, g.w };
        float bb4[4] = { bt.x, bt.y, bt.z, bt.w };
        half4v sil;
#pragma unroll
        for (int c = 0; c < 4; ++c) {
            float xs = xs4[c];
            float xq = fmaf((xs - mu) * rstd, gg[c] * KC, bb4[c] * KC);
            half8 h = spline8c(xq);
            // permB store: byte addr = j*4096 + c*1024 + lane*16 (coalesced)
            *(half8*)(Arow + (size_t)(j * 256 + c * 64 + lane) * 8) = h;
            sil[c] = (_Float16)(xs / (1.0f + exp2f(-xs * LOG2E)));
        }
        *(half4v*)(silu_out + idx * 4) = sil;   // 8B contiguous (identity order)
    }
}

// ---------------- GEMM (R3-verified, byte-identical: 148us, MfmaUtil 45%,
// VGPR 116, 0 conflicts): 256x256 tile, 8 waves (2Mx4N, per-wave 128x64),
// BK=64, double-buffered 128KB LDS, split-K=2. 4-phase quadrant schedule;
// counted vmcnt(2) per phase (never 0 mid-loop); slots consumed in issue
// order; XOR swizzle (row&7)<<4 applied both-sides.
__global__ __launch_bounds__(512, 2) void gemm_kernel(
        const _Float16* __restrict__ A, const _Float16* __restrict__ W,
        const float* __restrict__ bias, float* __restrict__ C,
        float* __restrict__ P, int ntiles, int gpz) {
    extern __shared__ __align__(16) char smem[];   // 2 x [A 32K | B 32K]
    const int tid  = threadIdx.x;
    const int wave = tid >> 6, lane = tid & 63;
    const int wm = wave >> 2, wn = wave & 3;       // 2M x 4N wave grid

    // bijective XCD swizzle (grid % 8 == 0): 4 bn-siblings per group
    const int lb = blockIdx.x;
    const int per_xcd = gridDim.x >> 5;
    const int xcd = lb & 7, sl = lb >> 3;
    const int g  = xcd * per_xcd + (sl >> 2);
    const int bn = sl & 3;
    const int bm = g / gpz;
    const int z  = g - bm * gpz;

    const int l8 = lane >> 3;
    const int chunkswz = ((lane & 7) ^ l8) << 4;
    const size_t zoff = (size_t)z * (KHALF * 2);
    const int gA[4] = {0, 128, 64, 192};
    const int gB[4] = {0, 128, 32, 160};
    const char* pA[4];
    const char* pB[4];
#pragma unroll
    for (int s = 0; s < 4; ++s) {
        pA[s] = (const char*)A + (size_t)(bm * 256 + gA[s] + wave * 8 + l8) * RB
                + zoff + chunkswz;
        pB[s] = (const char*)W + (size_t)(bn * 256 + gB[s] + (wave >> 2) * 64
                + (wave & 3) * 8 + l8) * RB + zoff + chunkswz;
    }

#define STAGE_A(s, nb, colb) __builtin_amdgcn_global_load_lds( \
        (const AS1 void*)(pA[s] + (colb)), \
        (AS3 void*)(smem + (nb) + (s) * 8192 + wave * 1024), 16, 0, 0)
#define STAGE_B(s, nb, colb) __builtin_amdgcn_global_load_lds( \
        (const AS1 void*)(pB[s] + (colb)), \
        (AS3 void*)(smem + (nb) + 32768 + (s) * 8192 + wave * 1024), 16, 0, 0)

    const int lm  = lane & 15;
    const int hi  = (lane >> 4) << 4;
    const int swz = (lm & 7) << 4;
    const int ck0 = (0  + hi) ^ swz;
    const int ck1 = (64 + hi) ^ swz;
    const int aB0 = (0 + wm) * 8192 + lm * 128;
    const int aB1 = (2 + wm) * 8192 + lm * 128;
    const int bB0 = 32768 + (0 + (wn >> 1)) * 8192 + ((wn & 1) * 32 + lm) * 128;
    const int bB1 = 32768 + (2 + (wn >> 1)) * 8192 + ((wn & 1) * 32 + lm) * 128;

    f32x4 acc[8][4] = {};

    STAGE_A(0, 0, 0); STAGE_A(1, 0, 0);
    STAGE_B(0, 0, 0); STAGE_B(1, 0, 0);
    STAGE_B(2, 0, 0); STAGE_B(3, 0, 0);
    STAGE_A(2, 0, 0); STAGE_A(3, 0, 0);
    asm volatile("s_waitcnt vmcnt(4)" ::: "memory");
    __builtin_amdgcn_s_barrier();

    for (int kt = 0; kt < ntiles; ++kt) {
        const int cb = (kt & 1) * 65536;
        const int nb = cb ^ 65536;
        const size_t col = (size_t)(kt + 1) * 128;
        const bool pref = (kt + 1 < ntiles);

        // ===== phase 0 =====
        half8 aF[4][2], bF[2][2];
#pragma unroll
        for (int m = 0; m < 4; ++m) {
            aF[m][0] = *(const half8*)(smem + cb + aB0 + m * 2048 + ck0);
            aF[m][1] = *(const half8*)(smem + cb + aB0 + m * 2048 + ck1);
        }
#pragma unroll
        for (int n = 0; n < 2; ++n) {
            bF[n][0] = *(const half8*)(smem + cb + bB0 + n * 2048 + ck0);
            bF[n][1] = *(const half8*)(smem + cb + bB0 + n * 2048 + ck1);
        }
        asm volatile("s_waitcnt vmcnt(2)" ::: "memory");
        if (pref) { STAGE_A(0, nb, col); STAGE_A(1, nb, col); }
        asm volatile("s_waitcnt lgkmcnt(8)" ::: "memory");
        __builtin_amdgcn_s_barrier();
        asm volatile("s_waitcnt lgkmcnt(0)" ::: "memory");
        __builtin_amdgcn_s_setprio(1);
#pragma unroll
        for (int n = 0; n < 2; ++n)
#pragma unroll
            for (int m = 0; m < 4; ++m)
                acc[m][n] = __builtin_amdgcn_mfma_f32_16x16x32_f16(aF[m][0], bF[n][0], acc[m][n], 0, 0, 0);
#pragma unroll
        for (int n = 0; n < 2; ++n)
#pragma unroll
            for (int m = 0; m < 4; ++m)
                acc[m][n] = __builtin_amdgcn_mfma_f32_16x16x32_f16(aF[m][1], bF[n][1], acc[m][n], 0, 0, 0);
        __builtin_amdgcn_s_setprio(0);
        __builtin_amdgcn_s_barrier();

        // ===== phase 1 =====
        half8 bG[2][2];
#pragma unroll
        for (int n = 0; n < 2; ++n) {
            bG[n][0] = *(const half8*)(smem + cb + bB1 + n * 2048 + ck0);
            bG[n][1] = *(const half8*)(smem + cb + bB1 + n * 2048 + ck1);
        }
        if (pref) {
            asm volatile("s_waitcnt vmcnt(2)" ::: "memory");
            STAGE_B(0, nb, col); STAGE_B(1, nb, col);
        } else {
            asm volatile("s_waitcnt vmcnt(0)" ::: "memory");
        }
        __builtin_amdgcn_s_barrier();
        asm volatile("s_waitcnt lgkmcnt(0)" ::: "memory");
        __builtin_amdgcn_s_setprio(1);
#pragma unroll
        for (int n = 0; n < 2; ++n)
#pragma unroll
            for (int m = 0; m < 4; ++m)
                acc[m][2 + n] = __builtin_amdgcn_mfma_f32_16x16x32_f16(aF[m][0], bG[n][0], acc[m][2 + n], 0, 0, 0);
#pragma unroll
        for (int n = 0; n < 2; ++n)
#pragma unroll
            for (int m = 0; m < 4; ++m)
                acc[m][2 + n] = __builtin_amdgcn_mfma_f32_16x16x32_f16(aF[m][1], bG[n][1], acc[m][2 + n], 0, 0, 0);
        __builtin_amdgcn_s_setprio(0);
        __builtin_amdgcn_s_barrier();

        // ===== phase 2 =====
        half8 aG[4][2];
#pragma unroll
        for (int m = 0; m < 4; ++m) {
            aG[m][0] = *(const half8*)(smem + cb + aB1 + m * 2048 + ck0);
            aG[m][1] = *(const half8*)(smem + cb + aB1 + m * 2048 + ck1);
        }
        if (pref) { STAGE_B(2, nb, col); STAGE_B(3, nb, col); }
        __builtin_amdgcn_s_barrier();
        asm volatile("s_waitcnt lgkmcnt(0)" ::: "memory");
        __builtin_amdgcn_s_setprio(1);
#pragma unroll
        for (int n = 0; n < 2; ++n)
#pragma unroll
            for (int m = 0; m < 4; ++m)
                acc[4 + m][n] = __builtin_amdgcn_mfma_f32_16x16x32_f16(aG[m][0], bF[n][0], acc[4 + m][n], 0, 0, 0);
#pragma unroll
        for (int n = 0; n < 2; ++n)
#pragma unroll
            for (int m = 0; m < 4; ++m)
                acc[4 + m][n] = __builtin_amdgcn_mfma_f32_16x16x32_f16(aG[m][1], bF[n][1], acc[4 + m][n], 0, 0, 0);
        __builtin_amdgcn_s_setprio(0);
        __builtin_amdgcn_s_barrier();

        // ===== phase 3 =====
        if (pref) {
            asm volatile("s_waitcnt vmcnt(2)" ::: "memory");
            STAGE_A(2, nb, col); STAGE_A(3, nb, col);
        }
        __builtin_amdgcn_s_barrier();
        __builtin_amdgcn_s_setprio(1);
#pragma unroll
        for (int n = 0; n < 2; ++n)
#pragma unroll
            for (int m = 0; m < 4; ++m)
                acc[4 + m][2 + n] = __builtin_amdgcn_mfma_f32_16x16x32_f16(aG[m][0], bG[n][0], acc[4 + m][2 + n], 0, 0, 0);
#pragma unroll
        for (int n = 0; n < 2; ++n)
#pragma unroll
            for (int m = 0; m < 4; ++m)
                acc[4 + m][2 + n] = __builtin_amdgcn_mfma_f32_16x16x32_f16(aG[m][1], bG[n][1], acc[4 + m][2 + n], 0, 0, 0);
        __builtin_amdgcn_s_setprio(0);
        __builtin_amdgcn_s_barrier();
    }

    const int cn  = lane & 15;
    const int rm4 = (lane >> 4) * 4;
    float* dst = z ? P : C;
#pragma unroll
    for (int nf = 0; nf < 4; ++nf) {
        int col = bn * 256 + wn * 64 + nf * 16 + cn;
        float bv = z ? 0.0f : bias[col];
#pragma unroll
        for (int mf = 0; mf < 8; ++mf) {
            int row = bm * 256 + wm * 128 + mf * 16 + rm4;
            float* cp = dst + (size_t)row * OUT_F + col;
#pragma unroll
            for (int r = 0; r < 4; ++r)
                cp[(size_t)r * OUT_F] = acc[mf][nf][r] + bv;
        }
    }
}

// ---- split-K reduction: C += P ----
__global__ __launch_bounds__(256) void reduce_kernel(float* __restrict__ C,
        const float* __restrict__ P) {
    const int n4 = M_ROWS * OUT_F / 4;
    float4* c4 = (float4*)C;
    const float4* p4 = (const float4*)P;
    for (int i = blockIdx.x * 256 + threadIdx.x; i < n4; i += 2048 * 256) {
        float4 a = c4[i];
        float4 b = p4[i];
        a.x += b.x; a.y += b.y; a.z += b.z; a.w += b.w;
        c4[i] = a;
    }
}

extern "C" void kernel_launch(void* const* d_in, const int* in_sizes, int n_in,
                              void* d_out, int out_size, void* d_ws, size_t ws_size,
                              hipStream_t stream) {
    const float* x     = (const float*)d_in[0];
    const float* gamma = (const float*)d_in[1];
    const float* beta  = (const float*)d_in[2];
    const float* sw    = (const float*)d_in[3];
    const float* bw    = (const float*)d_in[4];
    const float* bb    = (const float*)d_in[5];
    float* out = (float*)d_out;

    char* ws = (char*)d_ws;
    size_t offW = 0;
    size_t offA = (size_t)OUT_F * KDIM * 2;                       // 18.9 MB
    size_t offP = offA + (size_t)M_ROWS * KDIM * 2;               // +151 MB
    size_t need = offP + (size_t)M_ROWS * OUT_F * 4;              // +33.5 MB
    _Float16* Wb = (_Float16*)(ws + offW);
    _Float16* Ab = (_Float16*)(ws + offA);
    float*    Pb = (float*)(ws + offP);
    const int split = (ws_size >= need);

    static int s_attr = 0;
    if (!s_attr) {
        (void)hipFuncSetAttribute(reinterpret_cast<const void*>(gemm_kernel),
                            hipFuncAttributeMaxDynamicSharedMemorySize, 131072);
        s_attr = 1;
    }

    prep_kernel<<<A_BLOCKS + WS_BLOCKS + WSIL_BLOCKS, 256, 0, stream>>>(
        x, gamma, beta, sw, bw, Ab, Wb);
    if (split) {
        gemm_kernel<<<256, 512, 131072, stream>>>(Ab, Wb, bb, out, Pb, KHALF / 64, 2);
        reduce_kernel<<<2048, 256, 0, stream>>>(out, Pb);
    } else {
        gemm_kernel<<<128, 512, 131072, stream>>>(Ab, Wb, bb, out, Pb, KDIM / 64, 1);
    }
}

// Round 10
// 283.165 us; speedup vs baseline: 1.1134x; 1.0097x over previous
//
#include <hip/hip_runtime.h>
#include <hip/hip_bf16.h>
#include <stdint.h>

#define IN_F 1024
#define OUT_F 1024
#define NG 8
#define KSPLINE 8192            // IN_F * NG
#define KDIM 9216               // KSPLINE + IN_F
#define KHALF 4608              // split-K half (72 tiles of 64)
#define M_ROWS 8192
#define LOG2E 1.4426950408889634f
// KC = 1.75 * sqrt(log2(e)) : basis = exp(-((xn-c)*1.75)^2) = 2^(-(xn*KC - c*KC)^2)
#define KC 2.1019642153762872f
#define CQ0 (-2.0f * KC)                 // scaled leftmost grid point
#define DQ  (0.5714285714285714f * KC)   // scaled grid spacing
#define DQ2 1.4426950408889634f          // DQ*DQ == log2(e) exactly (1.75*4/7==1)
#define QCHAIN 0.1353352832366127f       // e^-2

// K-order permutation (basis region only; silu region identity). Applied
// IDENTICALLY to A columns and W columns -> invisible to the GEMM.
// p8(f) = (f>>8)*256 + (f&3)*64 + ((f>>2)&63)  [bijective per 256-block]

#define A_BLOCKS (M_ROWS / 4)           // 2048 (4 rows per block, wave-per-row)
#define WS_BLOCKS 4096                  // spline-W: 1M threads, 1 feature each
#define WSIL_BLOCKS 1024                // silu-W: 256K threads, 4 f32 each
#define RB (KDIM * 2)                   // A/W row bytes (18432)

using half4v = __attribute__((ext_vector_type(4))) _Float16;
using half8  = __attribute__((ext_vector_type(8))) _Float16;
using f32x4  = __attribute__((ext_vector_type(4))) float;

#define AS1 __attribute__((address_space(1)))
#define AS3 __attribute__((address_space(3)))

// geometric-chain RBF (validated R8, absmax 0.0625): 2 exp2 + 13 mul vs 8 exp2.
__device__ __forceinline__ half8 spline8c(float xq) {
    float d0 = xq - CQ0;
    float b  = __builtin_amdgcn_exp2f(-(d0 * d0));
    float r  = __builtin_amdgcn_exp2f(fmaf(2.0f * DQ, d0, -DQ2));
    half8 h;
#pragma unroll
    for (int g = 0; g < 8; ++g) {
        h[g] = (_Float16)b;
        if (g < 7) { b = b * r; r = r * QCHAIN; }
    }
    return h;
}

// ---- prep (R9-verified, byte-identical): A rows vectorized; W with permB.
__global__ __launch_bounds__(256) void prep_kernel(
        const float* __restrict__ x, const float* __restrict__ gamma,
        const float* __restrict__ beta, const float* __restrict__ sw,
        const float* __restrict__ bw, _Float16* __restrict__ A,
        _Float16* __restrict__ W) {
    const int b = blockIdx.x;
    if (b >= A_BLOCKS + WS_BLOCKS) {
        int t = (b - A_BLOCKS - WS_BLOCKS) * 256 + threadIdx.x;   // 0..256K
        int o = t >> 8, d4 = t & 255;
        f32x4 v = __builtin_nontemporal_load(&((const f32x4*)bw)[o * 256 + d4]);
        half4v h = { (_Float16)v.x, (_Float16)v.y, (_Float16)v.z, (_Float16)v.w };
        *(half4v*)(W + (size_t)o * KDIM + KSPLINE + d4 * 4) = h;
        return;
    }
    if (b >= A_BLOCKS) {
        int t = (b - A_BLOCKS) * 256 + threadIdx.x;               // 0..1M
        int o = t >> 10, f = t & 1023;
        const f32x4* src = &((const f32x4*)sw)[((size_t)o * 1024 + f) * 2];
        f32x4 v0 = __builtin_nontemporal_load(src);
        f32x4 v1 = __builtin_nontemporal_load(src + 1);
        half8 h = { (_Float16)v0.x, (_Float16)v0.y, (_Float16)v0.z, (_Float16)v0.w,
                    (_Float16)v1.x, (_Float16)v1.y, (_Float16)v1.z, (_Float16)v1.w };
        int p8 = (f >> 8) * 256 + (f & 3) * 64 + ((f >> 2) & 63);
        *(half8*)(W + (size_t)o * KDIM + p8 * 8) = h;
        return;
    }
    const int wave = threadIdx.x >> 6, lane = threadIdx.x & 63;
    const int row = b * 4 + wave;
    const f32x4* xr4 = (const f32x4*)(x + (size_t)row * IN_F);

    f32x4 xv[4];
    float s = 0.0f, s2 = 0.0f;
#pragma unroll
    for (int j = 0; j < 4; ++j) {
        f32x4 v = xr4[j * 64 + lane];
        xv[j] = v;
        s  += v.x + v.y + v.z + v.w;
        s2 += v.x * v.x + v.y * v.y + v.z * v.z + v.w * v.w;
    }
#pragma unroll
    for (int off = 32; off > 0; off >>= 1) {
        s  += __shfl_xor(s, off);
        s2 += __shfl_xor(s2, off);
    }
    float mu   = s * (1.0f / IN_F);
    float var  = s2 * (1.0f / IN_F) - mu * mu;
    float rstd = rsqrtf(var + 1e-5f);

    _Float16* Arow = A + (size_t)row * KDIM;
    _Float16* silu_out = Arow + KSPLINE;
#pragma unroll
    for (int j = 0; j < 4; ++j) {
        int idx = j * 64 + lane;
        f32x4 g  = ((const f32x4*)gamma)[idx];
        f32x4 bt = ((const f32x4*)beta)[idx];
        float xs4[4] = { xv[j].x, xv[j].y, xv[j].z, xv[j].w };
        float gg[4]  = { g.x, g.y, g.z, g.w };
        float bb4[4] = { bt.x, bt.y, bt.z, bt.w };
        half4v sil;
#pragma unroll
        for (int c = 0; c < 4; ++c) {
            float xs = xs4[c];
            float xq = fmaf((xs - mu) * rstd, gg[c] * KC, bb4[c] * KC);
            half8 h = spline8c(xq);
            *(half8*)(Arow + (size_t)(j * 256 + c * 64 + lane) * 8) = h;
            sil[c] = (_Float16)(xs / (1.0f + exp2f(-xs * LOG2E)));
        }
        *(half4v*)(silu_out + idx * 4) = sil;
    }
}

// ---------------- GEMM v10: R9 structure with frag reads moved INSIDE the
// previous phase's MFMA cluster, at NET-ZERO register cost via loop-carried
// WAR reuse (each set is re-read exactly when its old value is dead):
//   ph0 cluster reads bG  (B2B3 of t;   old bG dead after ph3(t-1))
//   ph1 cluster reads aG  (A2A3 of t;   old aG dead after ph3(t-1))
//   ph3 cluster reads aF,bF (A0A1/B0B1 of t+1; dead after ph1/ph2(t))
// Residency: every read source proven by that phase's pre-barrier vmcnt(2)
// + QUAD barrier (cross-wave); every read completes >=1 full phase before its
// consuming lgkmcnt(0). Staging issue order and vmcnt counts identical to R9.
__global__ __launch_bounds__(512, 2) void gemm_kernel(
        const _Float16* __restrict__ A, const _Float16* __restrict__ W,
        const float* __restrict__ bias, float* __restrict__ C,
        float* __restrict__ P, int ntiles, int gpz) {
    extern __shared__ __align__(16) char smem[];   // 2 x [A 32K | B 32K]
    const int tid  = threadIdx.x;
    const int wave = tid >> 6, lane = tid & 63;
    const int wm = wave >> 2, wn = wave & 3;       // 2M x 4N wave grid

    // bijective XCD swizzle (grid % 8 == 0): 4 bn-siblings per group
    const int lb = blockIdx.x;
    const int per_xcd = gridDim.x >> 5;
    const int xcd = lb & 7, sl = lb >> 3;
    const int g  = xcd * per_xcd + (sl >> 2);
    const int bn = sl & 3;
    const int bm = g / gpz;
    const int z  = g - bm * gpz;

    const int l8 = lane >> 3;
    const int chunkswz = ((lane & 7) ^ l8) << 4;
    const size_t zoff = (size_t)z * (KHALF * 2);
    const int gA[4] = {0, 128, 64, 192};
    const int gB[4] = {0, 128, 32, 160};
    const char* pA[4];
    const char* pB[4];
#pragma unroll
    for (int s = 0; s < 4; ++s) {
        pA[s] = (const char*)A + (size_t)(bm * 256 + gA[s] + wave * 8 + l8) * RB
                + zoff + chunkswz;
        pB[s] = (const char*)W + (size_t)(bn * 256 + gB[s] + (wave >> 2) * 64
                + (wave & 3) * 8 + l8) * RB + zoff + chunkswz;
    }

#define STAGE_A(s, nb, colb) __builtin_amdgcn_global_load_lds( \
        (const AS1 void*)(pA[s] + (colb)), \
        (AS3 void*)(smem + (nb) + (s) * 8192 + wave * 1024), 16, 0, 0)
#define STAGE_B(s, nb, colb) __builtin_amdgcn_global_load_lds( \
        (const AS1 void*)(pB[s] + (colb)), \
        (AS3 void*)(smem + (nb) + 32768 + (s) * 8192 + wave * 1024), 16, 0, 0)

    const int lm  = lane & 15;
    const int hi  = (lane >> 4) << 4;
    const int swz = (lm & 7) << 4;
    const int ck0 = (0  + hi) ^ swz;
    const int ck1 = (64 + hi) ^ swz;
    const int aB0 = (0 + wm) * 8192 + lm * 128;
    const int aB1 = (2 + wm) * 8192 + lm * 128;
    const int bB0 = 32768 + (0 + (wn >> 1)) * 8192 + ((wn & 1) * 32 + lm) * 128;
    const int bB1 = 32768 + (2 + (wn >> 1)) * 8192 + ((wn & 1) * 32 + lm) * 128;

    f32x4 acc[8][4] = {};
    half8 aF[4][2], bF[2][2], aG[4][2], bG[2][2];   // loop-carried frag sets

#define MFMA8(MB, NB2, Aa, Bb, KH)                                              \
    _Pragma("unroll")                                                           \
    for (int n = 0; n < 2; ++n)                                                 \
        _Pragma("unroll")                                                       \
        for (int m = 0; m < 4; ++m)                                             \
            acc[(MB)+m][(NB2)+n] = __builtin_amdgcn_mfma_f32_16x16x32_f16(      \
                Aa[m][KH], Bb[n][KH], acc[(MB)+m][(NB2)+n], 0, 0, 0);

    // ---- prologue: stage tile 0, pre-read aF/bF(t0) ----
    STAGE_A(0, 0, 0); STAGE_A(1, 0, 0);
    STAGE_B(0, 0, 0); STAGE_B(1, 0, 0);
    STAGE_B(2, 0, 0); STAGE_B(3, 0, 0);
    STAGE_A(2, 0, 0); STAGE_A(3, 0, 0);
    asm volatile("s_waitcnt vmcnt(4)" ::: "memory");   // A0A1,B0B1(t0) resident
    __builtin_amdgcn_s_barrier();                      // cross-wave publish
#pragma unroll
    for (int m = 0; m < 4; ++m) {
        aF[m][0] = *(const half8*)(smem + aB0 + m * 2048 + ck0);
        aF[m][1] = *(const half8*)(smem + aB0 + m * 2048 + ck1);
    }
#pragma unroll
    for (int n = 0; n < 2; ++n) {
        bF[n][0] = *(const half8*)(smem + bB0 + n * 2048 + ck0);
        bF[n][1] = *(const half8*)(smem + bB0 + n * 2048 + ck1);
    }

    for (int kt = 0; kt < ntiles; ++kt) {
        const int cb = (kt & 1) * 65536;
        const int nb = cb ^ 65536;
        const size_t col = (size_t)(kt + 1) * 128;
        const bool pref = (kt + 1 < ntiles);

        // ===== ph0: MFMA(mf0-3,nf0-1); cluster reads bG(t) =====
        asm volatile("s_waitcnt vmcnt(2)" ::: "memory");   // B2B3(t) proven
        if (pref) { STAGE_A(0, nb, col); STAGE_A(1, nb, col); }
        __builtin_amdgcn_s_barrier();
        asm volatile("s_waitcnt lgkmcnt(0)" ::: "memory"); // aF/bF reads done
        __builtin_amdgcn_s_setprio(1);
        MFMA8(0, 0, aF, bF, 0)
#pragma unroll
        for (int n = 0; n < 2; ++n) {
            bG[n][0] = *(const half8*)(smem + cb + bB1 + n * 2048 + ck0);
            bG[n][1] = *(const half8*)(smem + cb + bB1 + n * 2048 + ck1);
        }
        MFMA8(0, 0, aF, bF, 1)
        __builtin_amdgcn_s_setprio(0);
        __builtin_amdgcn_s_barrier();

        // ===== ph1: MFMA(mf0-3,nf2-3); cluster reads aG(t) =====
        if (pref) {
            asm volatile("s_waitcnt vmcnt(2)" ::: "memory");  // A2A3(t) proven
            STAGE_B(0, nb, col); STAGE_B(1, nb, col);
        } else {
            asm volatile("s_waitcnt vmcnt(0)" ::: "memory");
        }
        __builtin_amdgcn_s_barrier();
        asm volatile("s_waitcnt lgkmcnt(0)" ::: "memory"); // bG reads done
        __builtin_amdgcn_s_setprio(1);
        MFMA8(0, 2, aF, bG, 0)
#pragma unroll
        for (int m = 0; m < 4; ++m) {
            aG[m][0] = *(const half8*)(smem + cb + aB1 + m * 2048 + ck0);
            aG[m][1] = *(const half8*)(smem + cb + aB1 + m * 2048 + ck1);
        }
        MFMA8(0, 2, aF, bG, 1)
        __builtin_amdgcn_s_setprio(0);
        __builtin_amdgcn_s_barrier();

        // ===== ph2: MFMA(mf4-7,nf0-1); no reads =====
        if (pref) { STAGE_B(2, nb, col); STAGE_B(3, nb, col); }
        __builtin_amdgcn_s_barrier();
        asm volatile("s_waitcnt lgkmcnt(0)" ::: "memory"); // aG reads done
        __builtin_amdgcn_s_setprio(1);
        MFMA8(4, 0, aG, bF, 0)
        MFMA8(4, 0, aG, bF, 1)
        __builtin_amdgcn_s_setprio(0);
        __builtin_amdgcn_s_barrier();

        // ===== ph3: MFMA(mf4-7,nf2-3); cluster reads aF,bF(t+1) =====
        if (pref) {
            asm volatile("s_waitcnt vmcnt(2)" ::: "memory");  // A0A1,B0B1(t+1) proven
            STAGE_A(2, nb, col); STAGE_A(3, nb, col);
        } else {
            asm volatile("s_waitcnt vmcnt(0)" ::: "memory");
        }
        __builtin_amdgcn_s_barrier();
        asm volatile("s_waitcnt lgkmcnt(0)" ::: "memory");
        __builtin_amdgcn_s_setprio(1);
        MFMA8(4, 2, aG, bG, 0)
        if (pref) {
#pragma unroll
            for (int m = 0; m < 4; ++m) {
                aF[m][0] = *(const half8*)(smem + nb + aB0 + m * 2048 + ck0);
                aF[m][1] = *(const half8*)(smem + nb + aB0 + m * 2048 + ck1);
            }
#pragma unroll
            for (int n = 0; n < 2; ++n) {
                bF[n][0] = *(const half8*)(smem + nb + bB0 + n * 2048 + ck0);
                bF[n][1] = *(const half8*)(smem + nb + bB0 + n * 2048 + ck1);
            }
        }
        MFMA8(4, 2, aG, bG, 1)
        __builtin_amdgcn_s_setprio(0);
        __builtin_amdgcn_s_barrier();
    }

    const int cn  = lane & 15;
    const int rm4 = (lane >> 4) * 4;
    float* dst = z ? P : C;
#pragma unroll
    for (int nf = 0; nf < 4; ++nf) {
        int col = bn * 256 + wn * 64 + nf * 16 + cn;
        float bv = z ? 0.0f : bias[col];
#pragma unroll
        for (int mf = 0; mf < 8; ++mf) {
            int row = bm * 256 + wm * 128 + mf * 16 + rm4;
            float* cp = dst + (size_t)row * OUT_F + col;
#pragma unroll
            for (int r = 0; r < 4; ++r)
                cp[(size_t)r * OUT_F] = acc[mf][nf][r] + bv;
        }
    }
}

// ---- split-K reduction: C += P ----
__global__ __launch_bounds__(256) void reduce_kernel(float* __restrict__ C,
        const float* __restrict__ P) {
    const int n4 = M_ROWS * OUT_F / 4;
    float4* c4 = (float4*)C;
    const float4* p4 = (const float4*)P;
    for (int i = blockIdx.x * 256 + threadIdx.x; i < n4; i += 2048 * 256) {
        float4 a = c4[i];
        float4 b = p4[i];
        a.x += b.x; a.y += b.y; a.z += b.z; a.w += b.w;
        c4[i] = a;
    }
}

extern "C" void kernel_launch(void* const* d_in, const int* in_sizes, int n_in,
                              void* d_out, int out_size, void* d_ws, size_t ws_size,
                              hipStream_t stream) {
    const float* x     = (const float*)d_in[0];
    const float* gamma = (const float*)d_in[1];
    const float* beta  = (const float*)d_in[2];
    const float* sw    = (const float*)d_in[3];
    const float* bw    = (const float*)d_in[4];
    const float* bb    = (const float*)d_in[5];
    float* out = (float*)d_out;

    char* ws = (char*)d_ws;
    size_t offW = 0;
    size_t offA = (size_t)OUT_F * KDIM * 2;                       // 18.9 MB
    size_t offP = offA + (size_t)M_ROWS * KDIM * 2;               // +151 MB
    size_t need = offP + (size_t)M_ROWS * OUT_F * 4;              // +33.5 MB
    _Float16* Wb = (_Float16*)(ws + offW);
    _Float16* Ab = (_Float16*)(ws + offA);
    float*    Pb = (float*)(ws + offP);
    const int split = (ws_size >= need);

    static int s_attr = 0;
    if (!s_attr) {
        (void)hipFuncSetAttribute(reinterpret_cast<const void*>(gemm_kernel),
                            hipFuncAttributeMaxDynamicSharedMemorySize, 131072);
        s_attr = 1;
    }

    prep_kernel<<<A_BLOCKS + WS_BLOCKS + WSIL_BLOCKS, 256, 0, stream>>>(
        x, gamma, beta, sw, bw, Ab, Wb);
    if (split) {
        gemm_kernel<<<256, 512, 131072, stream>>>(Ab, Wb, bb, out, Pb, KHALF / 64, 2);
        reduce_kernel<<<2048, 256, 0, stream>>>(out, Pb);
    } else {
        gemm_kernel<<<128, 512, 131072, stream>>>(Ab, Wb, bb, out, Pb, KDIM / 64, 1);
    }
}

// Round 11
// 282.066 us; speedup vs baseline: 1.1178x; 1.0039x over previous
//
#include <hip/hip_runtime.h>
#include <hip/hip_bf16.h>
#include <stdint.h>

#define IN_F 1024
#define OUT_F 1024
#define NG 8
#define KSPLINE 8192            // IN_F * NG
#define KDIM 9216               // KSPLINE + IN_F
#define KHALF 4608              // split-K half (72 tiles of 64)
#define M_ROWS 8192
#define LOG2E 1.4426950408889634f
// KC = 1.75 * sqrt(log2(e)) : basis = exp(-((xn-c)*1.75)^2) = 2^(-(xn*KC - c*KC)^2)
#define KC 2.1019642153762872f
#define CQ0 (-2.0f * KC)                 // scaled leftmost grid point
#define DQ  (0.5714285714285714f * KC)   // scaled grid spacing
#define DQ2 1.4426950408889634f          // DQ*DQ == log2(e) exactly (1.75*4/7==1)
#define QCHAIN 0.1353352832366127f       // e^-2

// K-order permutation (basis region only; silu region identity). Applied
// IDENTICALLY to A columns and W columns -> invisible to the GEMM.
// p8(f) = (f>>8)*256 + (f&3)*64 + ((f>>2)&63)  [bijective per 256-block]

#define A_BLOCKS (M_ROWS / 4)           // 2048 (4 rows per block, wave-per-row)
#define WS_BLOCKS 4096                  // spline-W: 1M threads, 1 feature each
#define WSIL_BLOCKS 1024                // silu-W: 256K threads, 4 f32 each
#define RB (KDIM * 2)                   // A/W row bytes (18432)

using half4v = __attribute__((ext_vector_type(4))) _Float16;
using half8  = __attribute__((ext_vector_type(8))) _Float16;
using f32x4  = __attribute__((ext_vector_type(4))) float;

#define AS1 __attribute__((address_space(1)))
#define AS3 __attribute__((address_space(3)))

// geometric-chain RBF (validated R8, absmax 0.0625): 2 exp2 + 13 mul vs 8 exp2.
__device__ __forceinline__ half8 spline8c(float xq) {
    float d0 = xq - CQ0;
    float b  = __builtin_amdgcn_exp2f(-(d0 * d0));
    float r  = __builtin_amdgcn_exp2f(fmaf(2.0f * DQ, d0, -DQ2));
    half8 h;
#pragma unroll
    for (int g = 0; g < 8; ++g) {
        h[g] = (_Float16)b;
        if (g < 7) { b = b * r; r = r * QCHAIN; }
    }
    return h;
}

// ---- prep (R9-verified, byte-identical): A rows vectorized; W with permB.
__global__ __launch_bounds__(256) void prep_kernel(
        const float* __restrict__ x, const float* __restrict__ gamma,
        const float* __restrict__ beta, const float* __restrict__ sw,
        const float* __restrict__ bw, _Float16* __restrict__ A,
        _Float16* __restrict__ W) {
    const int b = blockIdx.x;
    if (b >= A_BLOCKS + WS_BLOCKS) {
        int t = (b - A_BLOCKS - WS_BLOCKS) * 256 + threadIdx.x;   // 0..256K
        int o = t >> 8, d4 = t & 255;
        f32x4 v = __builtin_nontemporal_load(&((const f32x4*)bw)[o * 256 + d4]);
        half4v h = { (_Float16)v.x, (_Float16)v.y, (_Float16)v.z, (_Float16)v.w };
        *(half4v*)(W + (size_t)o * KDIM + KSPLINE + d4 * 4) = h;
        return;
    }
    if (b >= A_BLOCKS) {
        int t = (b - A_BLOCKS) * 256 + threadIdx.x;               // 0..1M
        int o = t >> 10, f = t & 1023;
        const f32x4* src = &((const f32x4*)sw)[((size_t)o * 1024 + f) * 2];
        f32x4 v0 = __builtin_nontemporal_load(src);
        f32x4 v1 = __builtin_nontemporal_load(src + 1);
        half8 h = { (_Float16)v0.x, (_Float16)v0.y, (_Float16)v0.z, (_Float16)v0.w,
                    (_Float16)v1.x, (_Float16)v1.y, (_Float16)v1.z, (_Float16)v1.w };
        int p8 = (f >> 8) * 256 + (f & 3) * 64 + ((f >> 2) & 63);
        *(half8*)(W + (size_t)o * KDIM + p8 * 8) = h;
        return;
    }
    const int wave = threadIdx.x >> 6, lane = threadIdx.x & 63;
    const int row = b * 4 + wave;
    const f32x4* xr4 = (const f32x4*)(x + (size_t)row * IN_F);

    f32x4 xv[4];
    float s = 0.0f, s2 = 0.0f;
#pragma unroll
    for (int j = 0; j < 4; ++j) {
        f32x4 v = xr4[j * 64 + lane];
        xv[j] = v;
        s  += v.x + v.y + v.z + v.w;
        s2 += v.x * v.x + v.y * v.y + v.z * v.z + v.w * v.w;
    }
#pragma unroll
    for (int off = 32; off > 0; off >>= 1) {
        s  += __shfl_xor(s, off);
        s2 += __shfl_xor(s2, off);
    }
    float mu   = s * (1.0f / IN_F);
    float var  = s2 * (1.0f / IN_F) - mu * mu;
    float rstd = rsqrtf(var + 1e-5f);

    _Float16* Arow = A + (size_t)row * KDIM;
    _Float16* silu_out = Arow + KSPLINE;
#pragma unroll
    for (int j = 0; j < 4; ++j) {
        int idx = j * 64 + lane;
        f32x4 g  = ((const f32x4*)gamma)[idx];
        f32x4 bt = ((const f32x4*)beta)[idx];
        float xs4[4] = { xv[j].x, xv[j].y, xv[j].z, xv[j].w };
        float gg[4]  = { g.x, g.y, g.z, g.w };
        float bb4[4] = { bt.x, bt.y, bt.z, bt.w };
        half4v sil;
#pragma unroll
        for (int c = 0; c < 4; ++c) {
            float xs = xs4[c];
            float xq = fmaf((xs - mu) * rstd, gg[c] * KC, bb4[c] * KC);
            half8 h = spline8c(xq);
            *(half8*)(Arow + (size_t)(j * 256 + c * 64 + lane) * 8) = h;
            sil[c] = (_Float16)(xs / (1.0f + exp2f(-xs * LOG2E)));
        }
        *(half4v*)(silu_out + idx * 4) = sil;
    }
}

// ---------------- GEMM v11: R9 phase/read structure, staging pipeline
// deepened to t+2 (one FULL tile of extra prefetch distance). Slot-free
// analysis: A01(t+2) issuable at ph1(t) (slots last read ph0(t)), B01 ditto,
// B23(t+2) at ph2(t), A23(t+2) at ph3(t). Counted waits become
// vmcnt(10)/vmcnt(8)/vmcnt(12) — >=8 loads always in flight mid-loop, each
// proven load issued 6-7 phases (~4000cyc) earlier vs HBM ~900cyc. Last two
// tiles peeled with exact drain counts (10/8/4 then 2/0/0) since counted
// waits lose their proof when later loads were never issued.
__global__ __launch_bounds__(512, 2) void gemm_kernel(
        const _Float16* __restrict__ A, const _Float16* __restrict__ W,
        const float* __restrict__ bias, float* __restrict__ C,
        float* __restrict__ P, int ntiles, int gpz) {
    extern __shared__ __align__(16) char smem[];   // 2 x [A 32K | B 32K]
    const int tid  = threadIdx.x;
    const int wave = tid >> 6, lane = tid & 63;
    const int wm = wave >> 2, wn = wave & 3;       // 2M x 4N wave grid

    // bijective XCD swizzle (grid % 8 == 0): 4 bn-siblings per group
    const int lb = blockIdx.x;
    const int per_xcd = gridDim.x >> 5;
    const int xcd = lb & 7, sl = lb >> 3;
    const int g  = xcd * per_xcd + (sl >> 2);
    const int bn = sl & 3;
    const int bm = g / gpz;
    const int z  = g - bm * gpz;

    const int l8 = lane >> 3;
    const int chunkswz = ((lane & 7) ^ l8) << 4;
    const size_t zoff = (size_t)z * (KHALF * 2);
    const int gA[4] = {0, 128, 64, 192};
    const int gB[4] = {0, 128, 32, 160};
    const char* pA[4];
    const char* pB[4];
#pragma unroll
    for (int s = 0; s < 4; ++s) {
        pA[s] = (const char*)A + (size_t)(bm * 256 + gA[s] + wave * 8 + l8) * RB
                + zoff + chunkswz;
        pB[s] = (const char*)W + (size_t)(bn * 256 + gB[s] + (wave >> 2) * 64
                + (wave & 3) * 8 + l8) * RB + zoff + chunkswz;
    }

#define STAGE_A(s, nb, colb) __builtin_amdgcn_global_load_lds( \
        (const AS1 void*)(pA[s] + (colb)), \
        (AS3 void*)(smem + (nb) + (s) * 8192 + wave * 1024), 16, 0, 0)
#define STAGE_B(s, nb, colb) __builtin_amdgcn_global_load_lds( \
        (const AS1 void*)(pB[s] + (colb)), \
        (AS3 void*)(smem + (nb) + 32768 + (s) * 8192 + wave * 1024), 16, 0, 0)

    const int lm  = lane & 15;
    const int hi  = (lane >> 4) << 4;
    const int swz = (lm & 7) << 4;
    const int ck0 = (0  + hi) ^ swz;
    const int ck1 = (64 + hi) ^ swz;
    const int aB0 = (0 + wm) * 8192 + lm * 128;
    const int aB1 = (2 + wm) * 8192 + lm * 128;
    const int bB0 = 32768 + (0 + (wn >> 1)) * 8192 + ((wn & 1) * 32 + lm) * 128;
    const int bB1 = 32768 + (2 + (wn >> 1)) * 8192 + ((wn & 1) * 32 + lm) * 128;

    f32x4 acc[8][4] = {};

#define MFMA8(MB, NB2, Aa, Bb, KH)                                              \
    _Pragma("unroll")                                                           \
    for (int n = 0; n < 2; ++n)                                                 \
        _Pragma("unroll")                                                       \
        for (int m = 0; m < 4; ++m)                                             \
            acc[(MB)+m][(NB2)+n] = __builtin_amdgcn_mfma_f32_16x16x32_f16(      \
                Aa[m][KH], Bb[n][KH], acc[(MB)+m][(NB2)+n], 0, 0, 0);

#define VMW_(n) asm volatile("s_waitcnt vmcnt(" #n ")" ::: "memory")
#define VMW(n)  VMW_(n)

// one K-tile: phases/reads identical to R9; stages tile kt+2 into its own
// buffer (same parity); wait counts are macro literals.
#define GTILE(kt, W0, W1, W3, STG)                                              \
{                                                                               \
    const int cb = ((kt) & 1) * 65536;                                          \
    const size_t col2 = (size_t)((kt) + 2) * 128;                               \
    half8 aF[4][2], bF[2][2];                                                   \
    /* ===== ph0: reads A01(t)+B01(t); wait proves B23(t) ===== */              \
    _Pragma("unroll")                                                           \
    for (int m = 0; m < 4; ++m) {                                               \
        aF[m][0] = *(const half8*)(smem + cb + aB0 + m * 2048 + ck0);           \
        aF[m][1] = *(const half8*)(smem + cb + aB0 + m * 2048 + ck1);           \
    }                                                                           \
    _Pragma("unroll")                                                           \
    for (int n = 0; n < 2; ++n) {                                               \
        bF[n][0] = *(const half8*)(smem + cb + bB0 + n * 2048 + ck0);           \
        bF[n][1] = *(const half8*)(smem + cb + bB0 + n * 2048 + ck1);           \
    }                                                                           \
    VMW(W0);                                                                    \
    asm volatile("s_waitcnt lgkmcnt(8)" ::: "memory");                          \
    __builtin_amdgcn_s_barrier();                                               \
    asm volatile("s_waitcnt lgkmcnt(0)" ::: "memory");                          \
    __builtin_amdgcn_s_setprio(1);                                              \
    MFMA8(0, 0, aF, bF, 0)                                                      \
    MFMA8(0, 0, aF, bF, 1)                                                      \
    __builtin_amdgcn_s_setprio(0);                                              \
    __builtin_amdgcn_s_barrier();                                               \
    /* ===== ph1: reads B23(t); wait proves A23(t); stage A01+B01(t+2) ==== */  \
    half8 bG[2][2];                                                             \
    _Pragma("unroll")                                                           \
    for (int n = 0; n < 2; ++n) {                                               \
        bG[n][0] = *(const half8*)(smem + cb + bB1 + n * 2048 + ck0);           \
        bG[n][1] = *(const half8*)(smem + cb + bB1 + n * 2048 + ck1);           \
    }                                                                           \
    VMW(W1);                                                                    \
    if (STG) { STAGE_A(0, cb, col2); STAGE_A(1, cb, col2);                      \
               STAGE_B(0, cb, col2); STAGE_B(1, cb, col2); }                    \
    __builtin_amdgcn_s_barrier();                                               \
    asm volatile("s_waitcnt lgkmcnt(0)" ::: "memory");                          \
    __builtin_amdgcn_s_setprio(1);                                              \
    MFMA8(0, 2, aF, bG, 0)                                                      \
    MFMA8(0, 2, aF, bG, 1)                                                      \
    __builtin_amdgcn_s_setprio(0);                                              \
    __builtin_amdgcn_s_barrier();                                               \
    /* ===== ph2: reads A23(t); stage B23(t+2) ===== */                         \
    half8 aG[4][2];                                                             \
    _Pragma("unroll")                                                           \
    for (int m = 0; m < 4; ++m) {                                               \
        aG[m][0] = *(const half8*)(smem + cb + aB1 + m * 2048 + ck0);           \
        aG[m][1] = *(const half8*)(smem + cb + aB1 + m * 2048 + ck1);           \
    }                                                                           \
    if (STG) { STAGE_B(2, cb, col2); STAGE_B(3, cb, col2); }                    \
    __builtin_amdgcn_s_barrier();                                               \
    asm volatile("s_waitcnt lgkmcnt(0)" ::: "memory");                          \
    __builtin_amdgcn_s_setprio(1);                                              \
    MFMA8(4, 0, aG, bF, 0)                                                      \
    MFMA8(4, 0, aG, bF, 1)                                                      \
    __builtin_amdgcn_s_setprio(0);                                              \
    __builtin_amdgcn_s_barrier();                                               \
    /* ===== ph3: stage A23(t+2); wait proves A01+B01(t+1) ===== */             \
    if (STG) { STAGE_A(2, cb, col2); STAGE_A(3, cb, col2); }                    \
    VMW(W3);                                                                    \
    __builtin_amdgcn_s_barrier();                                               \
    __builtin_amdgcn_s_setprio(1);                                              \
    MFMA8(4, 2, aG, bG, 0)                                                      \
    MFMA8(4, 2, aG, bG, 1)                                                      \
    __builtin_amdgcn_s_setprio(0);                                              \
    __builtin_amdgcn_s_barrier();                                               \
}

    // ---- prologue: stage t0 AND t1 fully, in steady-state per-tile order ----
    STAGE_A(0, 0, 0); STAGE_A(1, 0, 0);
    STAGE_B(0, 0, 0); STAGE_B(1, 0, 0);
    STAGE_B(2, 0, 0); STAGE_B(3, 0, 0);
    STAGE_A(2, 0, 0); STAGE_A(3, 0, 0);
    STAGE_A(0, 65536, 128); STAGE_A(1, 65536, 128);
    STAGE_B(0, 65536, 128); STAGE_B(1, 65536, 128);
    STAGE_B(2, 65536, 128); STAGE_B(3, 65536, 128);
    STAGE_A(2, 65536, 128); STAGE_A(3, 65536, 128);
    VMW(12);                                   // A01,B01(t0) resident
    __builtin_amdgcn_s_barrier();

    for (int kt = 0; kt < ntiles - 2; ++kt)
        GTILE(kt, 10, 8, 12, true)
    GTILE(ntiles - 2, 10, 8, 4, false)         // drain tile: exact counts
    GTILE(ntiles - 1, 2, 0, 0, false)          // final tile

    const int cn  = lane & 15;
    const int rm4 = (lane >> 4) * 4;
    float* dst = z ? P : C;
#pragma unroll
    for (int nf = 0; nf < 4; ++nf) {
        int col = bn * 256 + wn * 64 + nf * 16 + cn;
        float bv = z ? 0.0f : bias[col];
#pragma unroll
        for (int mf = 0; mf < 8; ++mf) {
            int row = bm * 256 + wm * 128 + mf * 16 + rm4;
            float* cp = dst + (size_t)row * OUT_F + col;
#pragma unroll
            for (int r = 0; r < 4; ++r)
                cp[(size_t)r * OUT_F] = acc[mf][nf][r] + bv;
        }
    }
}

// ---- split-K reduction: C += P ----
__global__ __launch_bounds__(256) void reduce_kernel(float* __restrict__ C,
        const float* __restrict__ P) {
    const int n4 = M_ROWS * OUT_F / 4;
    float4* c4 = (float4*)C;
    const float4* p4 = (const float4*)P;
    for (int i = blockIdx.x * 256 + threadIdx.x; i < n4; i += 2048 * 256) {
        float4 a = c4[i];
        float4 b = p4[i];
        a.x += b.x; a.y += b.y; a.z += b.z; a.w += b.w;
        c4[i] = a;
    }
}

extern "C" void kernel_launch(void* const* d_in, const int* in_sizes, int n_in,
                              void* d_out, int out_size, void* d_ws, size_t ws_size,
                              hipStream_t stream) {
    const float* x     = (const float*)d_in[0];
    const float* gamma = (const float*)d_in[1];
    const float* beta  = (const float*)d_in[2];
    const float* sw    = (const float*)d_in[3];
    const float* bw    = (const float*)d_in[4];
    const float* bb    = (const float*)d_in[5];
    float* out = (float*)d_out;

    char* ws = (char*)d_ws;
    size_t offW = 0;
    size_t offA = (size_t)OUT_F * KDIM * 2;                       // 18.9 MB
    size_t offP = offA + (size_t)M_ROWS * KDIM * 2;               // +151 MB
    size_t need = offP + (size_t)M_ROWS * OUT_F * 4;              // +33.5 MB
    _Float16* Wb = (_Float16*)(ws + offW);
    _Float16* Ab = (_Float16*)(ws + offA);
    float*    Pb = (float*)(ws + offP);
    const int split = (ws_size >= need);

    static int s_attr = 0;
    if (!s_attr) {
        (void)hipFuncSetAttribute(reinterpret_cast<const void*>(gemm_kernel),
                            hipFuncAttributeMaxDynamicSharedMemorySize, 131072);
        s_attr = 1;
    }

    prep_kernel<<<A_BLOCKS + WS_BLOCKS + WSIL_BLOCKS, 256, 0, stream>>>(
        x, gamma, beta, sw, bw, Ab, Wb);
    if (split) {
        gemm_kernel<<<256, 512, 131072, stream>>>(Ab, Wb, bb, out, Pb, KHALF / 64, 2);
        reduce_kernel<<<2048, 256, 0, stream>>>(out, Pb);
    } else {
        gemm_kernel<<<128, 512, 131072, stream>>>(Ab, Wb, bb, out, Pb, KDIM / 64, 1);
    }
}